// Round 1
// baseline (2411.040 us; speedup 1.0000x reference)
//
#include <hip/hip_runtime.h>

// DUST_65085934403760 : LIHT sparse-coding + window attention, MI355X fp32.
// Shapes: D=2048, BATCH=2048, P=8, OMEGA=50, 10 iterations, L=1, CLAMP=150.
// Key restructures vs reference:
//   att[p,b] = <prev[p,b,:], u[b,:]>, u = (W^T z)@W  -> kills the 8 s_prev GEMMs
//   S@z with z 50-sparse -> gathered-row AXPY using S symmetric (row reads)
// Only 3 dense fp32 GEMMs remain (B = x@W^T, u, first LIHT iter with dense z_att).

#define DD 2048
#define NB 2048

// ---------------------------------------------------------------- GEMM (fp32)
// C[m,n] = sum_k A[m,k] * B'[k,n] (+ Cadd).  TRANSB=1: Bm is (N x K) row-major.
template<int TRANSB>
__global__ __launch_bounds__(256)
void gemm128(const float* __restrict__ A, const float* __restrict__ Bm,
             const float* __restrict__ Cadd, float* __restrict__ Cout) {
  __shared__ float As[16][132];
  __shared__ float Bs[16][132];
  const int tid = threadIdx.x;
  const int m0 = blockIdx.y * 128, n0 = blockIdx.x * 128;
  const int ty = tid >> 4, tx = tid & 15;
  const int lr = tid >> 1;           // 0..127 (row loader)
  const int lk = (tid & 1) * 8;      // 0 / 8
  const int bk = tid >> 4;           // 0..15  (NN B loader row)
  const int bn = (tid & 15) * 8;     // col
  float acc[8][8];
#pragma unroll
  for (int i = 0; i < 8; ++i)
#pragma unroll
    for (int j = 0; j < 8; ++j) acc[i][j] = 0.f;

  for (int k0 = 0; k0 < DD; k0 += 16) {
    float4 a0 = *(const float4*)&A[(size_t)(m0 + lr) * DD + k0 + lk];
    float4 a1 = *(const float4*)&A[(size_t)(m0 + lr) * DD + k0 + lk + 4];
    float4 b0, b1;
    if (TRANSB) {
      b0 = *(const float4*)&Bm[(size_t)(n0 + lr) * DD + k0 + lk];
      b1 = *(const float4*)&Bm[(size_t)(n0 + lr) * DD + k0 + lk + 4];
    } else {
      b0 = *(const float4*)&Bm[(size_t)(k0 + bk) * DD + n0 + bn];
      b1 = *(const float4*)&Bm[(size_t)(k0 + bk) * DD + n0 + bn + 4];
    }
    __syncthreads();
    As[lk+0][lr]=a0.x; As[lk+1][lr]=a0.y; As[lk+2][lr]=a0.z; As[lk+3][lr]=a0.w;
    As[lk+4][lr]=a1.x; As[lk+5][lr]=a1.y; As[lk+6][lr]=a1.z; As[lk+7][lr]=a1.w;
    if (TRANSB) {
      Bs[lk+0][lr]=b0.x; Bs[lk+1][lr]=b0.y; Bs[lk+2][lr]=b0.z; Bs[lk+3][lr]=b0.w;
      Bs[lk+4][lr]=b1.x; Bs[lk+5][lr]=b1.y; Bs[lk+6][lr]=b1.z; Bs[lk+7][lr]=b1.w;
    } else {
      *(float4*)&Bs[bk][bn]   = b0;
      *(float4*)&Bs[bk][bn+4] = b1;
    }
    __syncthreads();
#pragma unroll
    for (int kk = 0; kk < 16; ++kk) {
      float4 av0 = *(const float4*)&As[kk][ty*8];
      float4 av1 = *(const float4*)&As[kk][ty*8+4];
      float4 bv0 = *(const float4*)&Bs[kk][tx*8];
      float4 bv1 = *(const float4*)&Bs[kk][tx*8+4];
      float a[8]  = {av0.x,av0.y,av0.z,av0.w,av1.x,av1.y,av1.z,av1.w};
      float bb[8] = {bv0.x,bv0.y,bv0.z,bv0.w,bv1.x,bv1.y,bv1.z,bv1.w};
#pragma unroll
      for (int i = 0; i < 8; ++i)
#pragma unroll
        for (int j = 0; j < 8; ++j)
          acc[i][j] = fmaf(a[i], bb[j], acc[i][j]);
    }
  }
#pragma unroll
  for (int i = 0; i < 8; ++i) {
    size_t row = (size_t)(m0 + ty*8 + i) * DD + n0 + tx*8;
    float4 c0 = {acc[i][0],acc[i][1],acc[i][2],acc[i][3]};
    float4 c1 = {acc[i][4],acc[i][5],acc[i][6],acc[i][7]};
    if (Cadd) {
      float4 d0 = *(const float4*)&Cadd[row];
      float4 d1 = *(const float4*)&Cadd[row+4];
      c0.x+=d0.x; c0.y+=d0.y; c0.z+=d0.z; c0.w+=d0.w;
      c1.x+=d1.x; c1.y+=d1.y; c1.z+=d1.z; c1.w+=d1.w;
    }
    *(float4*)&Cout[row]   = c0;
    *(float4*)&Cout[row+4] = c1;
  }
}

// ------------------------------------------------------------ top-k threshold
// One wave per row. Exact rank-50 |value| via exponent bootstrap (ballot
// counts, avoids hot-bin LDS atomics) + 3 mantissa radix passes.
// Keeps a >= kth (duplicates kept, like jnp.where(a >= kth,...)).
__global__ __launch_bounds__(64)
void topk_kernel(const float* __restrict__ src, unsigned* __restrict__ sidx,
                 float* __restrict__ sval, int* __restrict__ scnt,
                 float* __restrict__ dense, float* __restrict__ mD,
                 int finalMode) {
  const int b = blockIdx.x;
  const int lane = threadIdx.x;
  const float* row = src + (size_t)b * DD;
  float v[32]; unsigned ab[32];
#pragma unroll
  for (int e4 = 0; e4 < 8; ++e4) {
    float4 t = *(const float4*)&row[e4*256 + lane*4];
    v[e4*4+0]=t.x; v[e4*4+1]=t.y; v[e4*4+2]=t.z; v[e4*4+3]=t.w;
  }
#pragma unroll
  for (int e = 0; e < 32; ++e) ab[e] = __float_as_uint(v[e]) & 0x7fffffffu;

  // wave max of |bits|
  unsigned mxb = 0;
#pragma unroll
  for (int e = 0; e < 32; ++e) mxb = ab[e] > mxb ? ab[e] : mxb;
  for (int off = 32; off; off >>= 1) {
    unsigned o = (unsigned)__shfl_down((int)mxb, off);
    mxb = o > mxb ? o : mxb;
  }
  mxb = (unsigned)__shfl((int)mxb, 0);
  const int emax = (int)(mxb >> 23);

  // exponent bootstrap: largest e with count(ab >= e<<23) >= 50
  int eStar = 0, cntAbove = 0;
  {
    int prevc = 0;
    for (int e = emax; e >= 0; --e) {
      unsigned T = ((unsigned)e) << 23;
      int c = 0;
#pragma unroll
      for (int k = 0; k < 32; ++k) c += (ab[k] >= T) ? 1 : 0;
      for (int off = 32; off; off >>= 1) c += __shfl_down(c, off);
      c = __shfl(c, 0);
      if (c >= 50) { eStar = e; cntAbove = prevc; break; }
      prevc = c;
    }
  }
  unsigned kth = ((unsigned)eStar) << 23;
  int kneed = 50 - cntAbove;

  __shared__ int hist[256];
  __shared__ int sh_sel, sh_kneed;
  for (int p = 0; p < 3; ++p) {
    const unsigned mask = (p==0) ? 0x7F800000u : (p==1) ? 0x7FFF8000u : 0x7FFFFF80u;
    const int sh = (p==0) ? 15 : (p==1) ? 7 : 0;
    for (int t = lane; t < 256; t += 64) hist[t] = 0;
    __syncthreads();
#pragma unroll
    for (int e = 0; e < 32; ++e)
      if ((ab[e] & mask) == kth) atomicAdd(&hist[(ab[e] >> sh) & 0xFF], 1);
    __syncthreads();
    int h0 = hist[lane*4+0], h1 = hist[lane*4+1], h2 = hist[lane*4+2], h3 = hist[lane*4+3];
    int s = h0 + h1 + h2 + h3;
    int x = s;
    for (int off = 1; off < 64; off <<= 1) {
      int y = __shfl_down(x, off);
      if (lane + off < 64) x += y;
    }
    int excl = x - s;            // suffix sum of later chunks
    int c3 = excl + h3, c2 = c3 + h2, c1 = c2 + h1, c0 = c1 + h0;
    if (c0 >= kneed && c1   < kneed) { sh_sel = lane*4+0; sh_kneed = kneed - c1;  }
    if (c1 >= kneed && c2   < kneed) { sh_sel = lane*4+1; sh_kneed = kneed - c2;  }
    if (c2 >= kneed && c3   < kneed) { sh_sel = lane*4+2; sh_kneed = kneed - c3;  }
    if (c3 >= kneed && excl < kneed) { sh_sel = lane*4+3; sh_kneed = kneed - excl;}
    __syncthreads();
    kth |= ((unsigned)sh_sel) << sh;
    kneed = sh_kneed;
    __syncthreads();
  }

  // extraction (compaction order-free; downstream is a sum)
  int base = 0;
#pragma unroll
  for (int e4 = 0; e4 < 8; ++e4) {
    float o[4];
#pragma unroll
    for (int q = 0; q < 4; ++q) {
      const int e = e4*4 + q;
      const bool sel = ab[e] >= kth;
      unsigned long long msk = __ballot(sel);
      int pre = __popcll(msk & ((1ull << lane) - 1ull));
      const unsigned gi = (unsigned)(e4*256 + lane*4 + q);
      if (sel) {
        int slot = base + pre;
        if (slot < 64) { sidx[b*64+slot] = gi; sval[b*64+slot] = v[e]; }
        if (finalMode) atomicAdd(&mD[gi & 1023u], v[e]*v[e]);
      }
      base += __popcll(msk);
      o[q] = sel ? v[e] : 0.f;
    }
    if (finalMode) {
      float4 t = {o[0],o[1],o[2],o[3]};
      *(float4*)&dense[(size_t)b*DD + e4*256 + lane*4] = t;
    }
  }
  if (lane == 0) scnt[b] = base < 64 ? base : 64;
}

// --------------------------------------------------- sparse apply (M@z etc.)
// out[b, i0+r] = baseB[b,i0+r] + sum_t sval[b,t] * M[sidx[b,t], i0+r]
// (S symmetric -> this computes B + S z; with M=W_d it computes W^T z.)
__global__ __launch_bounds__(256)
void spapply_kernel(const float* __restrict__ M, const float* __restrict__ baseB,
                    float* __restrict__ out, const unsigned* __restrict__ sidx,
                    const float* __restrict__ sval, const int* __restrict__ scnt) {
  __shared__ float Mt[DD * 5];               // column tile (4 cols, stride 5)
  const int tid = threadIdx.x;
  const int i0 = blockIdx.x * 4;
  for (int j = tid; j < DD; j += 256) {
    float4 m4 = *(const float4*)&M[(size_t)j*DD + i0];
    Mt[j*5+0]=m4.x; Mt[j*5+1]=m4.y; Mt[j*5+2]=m4.z; Mt[j*5+3]=m4.w;
  }
  __syncthreads();
  const int r = tid & 3, bb = tid >> 2;      // 64 batch slots x 4 cols
  for (int g = 0; g < 32; ++g) {
    const int b = g*64 + bb;
    float acc = baseB ? baseB[(size_t)b*DD + i0 + r] : 0.f;
    const int nc = scnt[b];
    const unsigned* ip = sidx + b*64;
    const float* vp = sval + b*64;
    for (int t = 0; t < nc; ++t)
      acc = fmaf(vp[t], Mt[ip[t]*5 + r], acc);
    out[(size_t)b*DD + i0 + r] = acc;
  }
}

// ------------------------------------------------------------- attention bits
__global__ __launch_bounds__(256)
void attdot_kernel(const float* __restrict__ prev, const float* __restrict__ U,
                   float* __restrict__ att) {
  const int b = blockIdx.x, p = blockIdx.y, tid = threadIdx.x;
  const float* pr = prev + ((size_t)p*NB + b) * DD;
  const float* u  = U + (size_t)b * DD;
  float s = 0.f;
#pragma unroll
  for (int h = 0; h < 2; ++h) {
    int i = (tid + h*256) * 4;
    float4 a = *(const float4*)&pr[i];
    float4 c = *(const float4*)&u[i];
    s += a.x*c.x + a.y*c.y + a.z*c.z + a.w*c.w;
  }
  for (int off = 32; off; off >>= 1) s += __shfl_down(s, off);
  __shared__ float ps[4];
  if ((tid & 63) == 0) ps[tid >> 6] = s;
  __syncthreads();
  if (tid == 0) att[(size_t)p*NB + b] = ps[0]+ps[1]+ps[2]+ps[3];
}

__global__ __launch_bounds__(256)
void softmax_kernel(const float* __restrict__ att, float* __restrict__ attw) {
  const int p = blockIdx.x, tid = threadIdx.x;
  const float* a = att + (size_t)p*NB;
  float loc[8]; float mx = -3.4e38f;
#pragma unroll
  for (int h = 0; h < 8; ++h) { loc[h] = a[tid + h*256]; mx = fmaxf(mx, loc[h]); }
  for (int off = 32; off; off >>= 1) mx = fmaxf(mx, __shfl_down(mx, off));
  __shared__ float ps[4]; __shared__ float sh_m, sh_s;
  if ((tid & 63) == 0) ps[tid >> 6] = mx;
  __syncthreads();
  if (tid == 0) sh_m = fmaxf(fmaxf(ps[0],ps[1]), fmaxf(ps[2],ps[3]));
  __syncthreads();
  const float m = sh_m;
  float sum = 0.f;
#pragma unroll
  for (int h = 0; h < 8; ++h) sum += expf(loc[h] - m);
  for (int off = 32; off; off >>= 1) sum += __shfl_down(sum, off);
  __syncthreads();
  if ((tid & 63) == 0) ps[tid >> 6] = sum;
  __syncthreads();
  if (tid == 0) sh_s = ps[0]+ps[1]+ps[2]+ps[3];
  __syncthreads();
  const float inv = 1.0f / sh_s;
#pragma unroll
  for (int h = 0; h < 8; ++h) attw[(size_t)p*NB + tid + h*256] = expf(loc[h] - m) * inv;
}

__global__ __launch_bounds__(256)
void zatt_kernel(const float* __restrict__ prev, const float* __restrict__ attw,
                 const float* __restrict__ lam, float* __restrict__ Z) {
  const int b = blockIdx.x, tid = threadIdx.x;
  __shared__ float w[8];
  if (tid < 8) w[tid] = attw[(size_t)tid*NB + b];
  __syncthreads();
  const float l2 = lam[0];
#pragma unroll
  for (int h = 0; h < 2; ++h) {
    int i = (tid + h*256) * 4;
    float4 acc = {0.f,0.f,0.f,0.f};
#pragma unroll
    for (int p = 0; p < 8; ++p) {
      float4 pv = *(const float4*)&prev[((size_t)p*NB + b)*DD + i];
      float wp = w[p];
      acc.x += wp * fminf(fmaxf(pv.x, -150.f), 150.f);
      acc.y += wp * fminf(fmaxf(pv.y, -150.f), 150.f);
      acc.z += wp * fminf(fmaxf(pv.z, -150.f), 150.f);
      acc.w += wp * fminf(fmaxf(pv.w, -150.f), 150.f);
    }
    acc.x *= l2; acc.y *= l2; acc.z *= l2; acc.w *= l2;
    *(float4*)&Z[(size_t)b*DD + i] = acc;
  }
}

__global__ __launch_bounds__(256)
void norm_kernel(float* __restrict__ mD) {
  const int tid = threadIdx.x;
  float v[4]; float mn = 3.4e38f, mx = -3.4e38f;
#pragma unroll
  for (int h = 0; h < 4; ++h) {
    v[h] = mD[tid + h*256];
    mn = fminf(mn, v[h]); mx = fmaxf(mx, v[h]);
  }
  for (int off = 32; off; off >>= 1) {
    mn = fminf(mn, __shfl_down(mn, off));
    mx = fmaxf(mx, __shfl_down(mx, off));
  }
  __shared__ float pmn[4], pmx[4]; __shared__ float smn, smx;
  if ((tid & 63) == 0) { pmn[tid>>6] = mn; pmx[tid>>6] = mx; }
  __syncthreads();
  if (tid == 0) {
    smn = fminf(fminf(pmn[0],pmn[1]), fminf(pmn[2],pmn[3]));
    smx = fmaxf(fmaxf(pmx[0],pmx[1]), fmaxf(pmx[2],pmx[3]));
  }
  __syncthreads();
  const float d = smx - smn + 1e-8f;
#pragma unroll
  for (int h = 0; h < 4; ++h) mD[tid + h*256] = (v[h] - smn) / d;
}

// ----------------------------------------------------------------- launcher
extern "C" void kernel_launch(void* const* d_in, const int* in_sizes, int n_in,
                              void* d_out, int out_size, void* d_ws, size_t ws_size,
                              hipStream_t stream) {
  const float* x    = (const float*)d_in[0];   // (2048, 2048)
  const float* prev = (const float*)d_in[1];   // (8, 2048, 2048)
  const float* Wd   = (const float*)d_in[2];   // (2048, 2048)
  const float* S    = (const float*)d_in[3];   // (2048, 2048) symmetric
  const float* lam  = (const float*)d_in[4];   // scalar

  float* out   = (float*)d_out;
  float* mD    = out;                 // 1024
  float* zlast = out + 1024;          // dense z_last; doubles as U scratch early

  // workspace layout (~49.3 MB)
  float* B  = (float*)d_ws;                       // 16 MB
  float* C  = B  + (1u << 22);                    // 16 MB
  float* X1 = C  + (1u << 22);                    // 16 MB (s_t, then z_att)
  unsigned* sidx = (unsigned*)(X1 + (1u << 22));  // 2048*64 u32
  float*    sval = (float*)(sidx + 2048*64);      // 2048*64 f32
  int*      scnt = (int*)(sval + 2048*64);        // 2048
  float*    att  = (float*)(scnt + 2048);         // 8*2048
  float*    attw = att + 8*2048;                  // 8*2048
  float*    U    = zlast;

  const dim3 gGemm(16, 16);

  // B = x @ Wd^T
  gemm128<1><<<gGemm, 256, 0, stream>>>(x, Wd, nullptr, B);
  // z1 = hard_thr(B)
  topk_kernel<<<NB, 64, 0, stream>>>(B, sidx, sval, scnt, nullptr, nullptr, 0);
  // C = B + S z1  (sparse)
  spapply_kernel<<<512, 256, 0, stream>>>(S, B, C, sidx, sval, scnt);
  // z2 = hard_thr(C)
  topk_kernel<<<NB, 64, 0, stream>>>(C, sidx, sval, scnt, nullptr, nullptr, 0);
  // s_t = Wd^T z2  (sparse rows of Wd)
  spapply_kernel<<<512, 256, 0, stream>>>(Wd, nullptr, X1, sidx, sval, scnt);
  // u = s_t @ Wd
  gemm128<0><<<gGemm, 256, 0, stream>>>(X1, Wd, nullptr, U);
  // att[p,b] = <prev[p,b,:], u[b,:]>
  attdot_kernel<<<dim3(NB, 8), 256, 0, stream>>>(prev, U, att);
  // softmax over batch axis
  softmax_kernel<<<8, 256, 0, stream>>>(att, attw);
  // z_att = lambda2 * sum_p attw * clip(prev)
  zatt_kernel<<<NB, 256, 0, stream>>>(prev, attw, lam, X1);
  // iter 1 (dense z): C = B + z_att @ S   (S symmetric)
  gemm128<0><<<gGemm, 256, 0, stream>>>(X1, S, B, C);

  for (int it = 0; it < 10; ++it) {
    if (it > 0)
      spapply_kernel<<<512, 256, 0, stream>>>(S, B, C, sidx, sval, scnt);
    const int fin = (it == 9);
    if (fin) hipMemsetAsync(mD, 0, 1024 * sizeof(float), stream);
    topk_kernel<<<NB, 64, 0, stream>>>(C, sidx, sval, scnt,
                                       fin ? zlast : nullptr,
                                       fin ? mD : nullptr, fin);
  }
  // mD_norm = (mD - min) / (max - min + 1e-8)
  norm_kernel<<<1, 256, 0, stream>>>(mD);
}

// Round 3
// 1853.626 us; speedup vs baseline: 1.3007x; 1.3007x over previous
//
#include <hip/hip_runtime.h>

// DUST_65085934403760 : LIHT sparse-coding + window attention, MI355X fp32.
// D=2048, BATCH=2048, P=8, OMEGA=50, 10 iters, L=1, CLAMP=150.
// Round 3: all-fp32, BIT-IDENTICAL summation order to round 1 (which passed):
//   - gemm_f32: 128x64 tiles (512 blocks = 2/CU), double-buffered LDS,
//     ascending-k single fma chain per output, Cadd in epilogue.
//   - spapply2: one block per batch row, coalesced S-row gather, base-first acc.
// bf16 MFMA path removed: round-2 showed 1e-5-scale GEMM error flips top-k
// selections (Output1 absmax 3.08 = one flipped entry).

#define DD 2048
#define NB 2048

// ------------------------------------------------------------- GEMM (fp32)
// C[m,n] = sum_k A[m,k] * (TRANSB ? Bm[n,k] : Bm[k,n])  (+ Cadd[m,n] at end)
// Tile 128(m) x 64(n), k-chunk 16, 256 threads, 8x4 outputs/thread.
template<int TRANSB, int ADD>
__global__ __launch_bounds__(256)
void gemm_f32(const float* __restrict__ A, const float* __restrict__ Bm,
              const float* __restrict__ Cadd, float* __restrict__ Cout) {
  __shared__ float As[2][16][132];   // [k][m], padded
  __shared__ float Bs[2][16][68];    // [k][n], padded
  const int tid = threadIdx.x;
  const int m0 = blockIdx.y * 128, n0 = blockIdx.x * 64;
  // A staging: 128 rows x 16 k -> 8 floats/thread
  const int lr = tid >> 1, lk = (tid & 1) * 8;
  // B staging
  const int br  = tid >> 2, bk1 = (tid & 3) * 4;   // TRANSB=1: 64 rows x 16 k
  const int bk0 = tid >> 4, bn  = (tid & 15) * 4;  // TRANSB=0: 16 rows x 64 n
  const int ty = tid >> 4, tx = tid & 15;          // output: m=ty*8+, n=tx*4+

  float acc[8][4];
#pragma unroll
  for (int i = 0; i < 8; ++i)
#pragma unroll
    for (int j = 0; j < 4; ++j) acc[i][j] = 0.f;

  const float* Arow = A + (size_t)(m0 + lr) * DD + lk;
  const float* Bp = TRANSB ? (Bm + (size_t)(n0 + br) * DD + bk1)
                           : (Bm + (size_t)bk0 * DD + n0 + bn);

  float4 a0 = *(const float4*)(Arow);
  float4 a1 = *(const float4*)(Arow + 4);
  float4 bv = *(const float4*)(Bp);

  // stage chunk 0
  {
    As[0][lk+0][lr]=a0.x; As[0][lk+1][lr]=a0.y; As[0][lk+2][lr]=a0.z; As[0][lk+3][lr]=a0.w;
    As[0][lk+4][lr]=a1.x; As[0][lk+5][lr]=a1.y; As[0][lk+6][lr]=a1.z; As[0][lk+7][lr]=a1.w;
    if (TRANSB) {
      Bs[0][bk1+0][br]=bv.x; Bs[0][bk1+1][br]=bv.y; Bs[0][bk1+2][br]=bv.z; Bs[0][bk1+3][br]=bv.w;
    } else {
      *(float4*)&Bs[0][bk0][bn] = bv;
    }
  }
  __syncthreads();

  const int NC = DD / 16;
  for (int c = 0; c < NC; ++c) {
    const int buf = c & 1;
    if (c + 1 < NC) {
      const int k1 = (c + 1) * 16;
      a0 = *(const float4*)(Arow + k1);
      a1 = *(const float4*)(Arow + k1 + 4);
      bv = TRANSB ? *(const float4*)(Bp + k1)
                  : *(const float4*)(Bp + (size_t)k1 * DD);
    }
#pragma unroll
    for (int kk = 0; kk < 16; ++kk) {
      float4 av0 = *(const float4*)&As[buf][kk][ty*8];
      float4 av1 = *(const float4*)&As[buf][kk][ty*8+4];
      float4 bq  = *(const float4*)&Bs[buf][kk][tx*4];
      float a[8]  = {av0.x,av0.y,av0.z,av0.w,av1.x,av1.y,av1.z,av1.w};
      float bb[4] = {bq.x,bq.y,bq.z,bq.w};
#pragma unroll
      for (int i = 0; i < 8; ++i)
#pragma unroll
        for (int j = 0; j < 4; ++j)
          acc[i][j] = fmaf(a[i], bb[j], acc[i][j]);
    }
    if (c + 1 < NC) {
      const int nb = buf ^ 1;
      __syncthreads();
      As[nb][lk+0][lr]=a0.x; As[nb][lk+1][lr]=a0.y; As[nb][lk+2][lr]=a0.z; As[nb][lk+3][lr]=a0.w;
      As[nb][lk+4][lr]=a1.x; As[nb][lk+5][lr]=a1.y; As[nb][lk+6][lr]=a1.z; As[nb][lk+7][lr]=a1.w;
      if (TRANSB) {
        Bs[nb][bk1+0][br]=bv.x; Bs[nb][bk1+1][br]=bv.y; Bs[nb][bk1+2][br]=bv.z; Bs[nb][bk1+3][br]=bv.w;
      } else {
        *(float4*)&Bs[nb][bk0][bn] = bv;
      }
      __syncthreads();
    }
  }

#pragma unroll
  for (int i = 0; i < 8; ++i) {
    size_t row = (size_t)(m0 + ty*8 + i) * DD + n0 + tx*4;
    float4 c0 = {acc[i][0], acc[i][1], acc[i][2], acc[i][3]};
    if (ADD) {
      float4 d0 = *(const float4*)&Cadd[row];
      c0.x += d0.x; c0.y += d0.y; c0.z += d0.z; c0.w += d0.w;
    }
    *(float4*)&Cout[row] = c0;
  }
}

// ------------------------------------------------------------ top-k threshold
// One wave per row. Exact rank-50 |value| via exponent bootstrap + 3 mantissa
// radix passes. Keeps a >= kth (duplicates kept, like jnp.where(a >= kth,...)).
__global__ __launch_bounds__(64)
void topk_kernel(const float* __restrict__ src, unsigned* __restrict__ sidx,
                 float* __restrict__ sval, int* __restrict__ scnt,
                 float* __restrict__ dense, float* __restrict__ mD,
                 int finalMode) {
  const int b = blockIdx.x;
  const int lane = threadIdx.x;
  const float* row = src + (size_t)b * DD;
  float v[32]; unsigned ab[32];
#pragma unroll
  for (int e4 = 0; e4 < 8; ++e4) {
    float4 t = *(const float4*)&row[e4*256 + lane*4];
    v[e4*4+0]=t.x; v[e4*4+1]=t.y; v[e4*4+2]=t.z; v[e4*4+3]=t.w;
  }
#pragma unroll
  for (int e = 0; e < 32; ++e) ab[e] = __float_as_uint(v[e]) & 0x7fffffffu;

  unsigned mxb = 0;
#pragma unroll
  for (int e = 0; e < 32; ++e) mxb = ab[e] > mxb ? ab[e] : mxb;
  for (int off = 32; off; off >>= 1) {
    unsigned o = (unsigned)__shfl_down((int)mxb, off);
    mxb = o > mxb ? o : mxb;
  }
  mxb = (unsigned)__shfl((int)mxb, 0);
  const int emax = (int)(mxb >> 23);

  int eStar = 0, cntAbove = 0;
  {
    int prevc = 0;
    for (int e = emax; e >= 0; --e) {
      unsigned T = ((unsigned)e) << 23;
      int c = 0;
#pragma unroll
      for (int k = 0; k < 32; ++k) c += (ab[k] >= T) ? 1 : 0;
      for (int off = 32; off; off >>= 1) c += __shfl_down(c, off);
      c = __shfl(c, 0);
      if (c >= 50) { eStar = e; cntAbove = prevc; break; }
      prevc = c;
    }
  }
  unsigned kth = ((unsigned)eStar) << 23;
  int kneed = 50 - cntAbove;

  __shared__ int hist[256];
  __shared__ int sh_sel, sh_kneed;
  for (int p = 0; p < 3; ++p) {
    const unsigned mask = (p==0) ? 0x7F800000u : (p==1) ? 0x7FFF8000u : 0x7FFFFF80u;
    const int sh = (p==0) ? 15 : (p==1) ? 7 : 0;
    for (int t = lane; t < 256; t += 64) hist[t] = 0;
    __syncthreads();
#pragma unroll
    for (int e = 0; e < 32; ++e)
      if ((ab[e] & mask) == kth) atomicAdd(&hist[(ab[e] >> sh) & 0xFF], 1);
    __syncthreads();
    int h0 = hist[lane*4+0], h1 = hist[lane*4+1], h2 = hist[lane*4+2], h3 = hist[lane*4+3];
    int s = h0 + h1 + h2 + h3;
    int x = s;
    for (int off = 1; off < 64; off <<= 1) {
      int y = __shfl_down(x, off);
      if (lane + off < 64) x += y;
    }
    int excl = x - s;
    int c3 = excl + h3, c2 = c3 + h2, c1 = c2 + h1, c0 = c1 + h0;
    if (c0 >= kneed && c1   < kneed) { sh_sel = lane*4+0; sh_kneed = kneed - c1;  }
    if (c1 >= kneed && c2   < kneed) { sh_sel = lane*4+1; sh_kneed = kneed - c2;  }
    if (c2 >= kneed && c3   < kneed) { sh_sel = lane*4+2; sh_kneed = kneed - c3;  }
    if (c3 >= kneed && excl < kneed) { sh_sel = lane*4+3; sh_kneed = kneed - excl;}
    __syncthreads();
    kth |= ((unsigned)sh_sel) << sh;
    kneed = sh_kneed;
    __syncthreads();
  }

  int base = 0;
#pragma unroll
  for (int e4 = 0; e4 < 8; ++e4) {
    float o[4];
#pragma unroll
    for (int qq = 0; qq < 4; ++qq) {
      const int e = e4*4 + qq;
      const bool sel = ab[e] >= kth;
      unsigned long long msk = __ballot(sel);
      int pre = __popcll(msk & ((1ull << lane) - 1ull));
      const unsigned gi = (unsigned)(e4*256 + lane*4 + qq);
      if (sel) {
        int slot = base + pre;
        if (slot < 64) { sidx[b*64+slot] = gi; sval[b*64+slot] = v[e]; }
        if (finalMode) atomicAdd(&mD[gi & 1023u], v[e]*v[e]);
      }
      base += __popcll(msk);
      o[qq] = sel ? v[e] : 0.f;
    }
    if (finalMode) {
      float4 t = {o[0],o[1],o[2],o[3]};
      *(float4*)&dense[(size_t)b*DD + e4*256 + lane*4] = t;
    }
  }
  if (lane == 0) scnt[b] = base < 64 ? base : 64;
}

// -------------------------------------------- sparse apply, one block per row
// out[b,:] = (HASBASE ? base[b,:] : 0) + sum_t sval[b,t] * M[sidx[b,t], :]
// Base loaded FIRST into the accumulator -> identical fma chain to round 1.
template<int HASBASE>
__global__ __launch_bounds__(256)
void spapply2(const float* __restrict__ M, const float* __restrict__ baseB,
              float* __restrict__ outF, const unsigned* __restrict__ sidx,
              const float* __restrict__ sval, const int* __restrict__ scnt) {
  const int b = blockIdx.x, tid = threadIdx.x;
  __shared__ unsigned si[64]; __shared__ float sv[64]; __shared__ int snc;
  if (tid < 64) { si[tid] = sidx[b*64+tid]; sv[tid] = sval[b*64+tid]; }
  if (tid == 0) snc = scnt[b];
  __syncthreads();
  const int nc = snc;
  const size_t o4 = (size_t)b * 512 + tid;
  float4 a0, a1;
  if (HASBASE) {
    a0 = ((const float4*)baseB)[o4];
    a1 = ((const float4*)baseB)[o4 + 256];
  } else {
    a0 = make_float4(0.f,0.f,0.f,0.f);
    a1 = make_float4(0.f,0.f,0.f,0.f);
  }
  int t = 0;
  for (; t + 2 <= nc; t += 2) {
    unsigned j0 = si[t], j1 = si[t+1];
    float v0 = sv[t], v1 = sv[t+1];
    const float4* r0 = (const float4*)(M + (size_t)j0 * DD);
    const float4* r1 = (const float4*)(M + (size_t)j1 * DD);
    float4 m00 = r0[tid], m01 = r0[tid + 256];
    float4 m10 = r1[tid], m11 = r1[tid + 256];
    a0.x = fmaf(v0, m00.x, a0.x); a0.y = fmaf(v0, m00.y, a0.y);
    a0.z = fmaf(v0, m00.z, a0.z); a0.w = fmaf(v0, m00.w, a0.w);
    a1.x = fmaf(v0, m01.x, a1.x); a1.y = fmaf(v0, m01.y, a1.y);
    a1.z = fmaf(v0, m01.z, a1.z); a1.w = fmaf(v0, m01.w, a1.w);
    a0.x = fmaf(v1, m10.x, a0.x); a0.y = fmaf(v1, m10.y, a0.y);
    a0.z = fmaf(v1, m10.z, a0.z); a0.w = fmaf(v1, m10.w, a0.w);
    a1.x = fmaf(v1, m11.x, a1.x); a1.y = fmaf(v1, m11.y, a1.y);
    a1.z = fmaf(v1, m11.z, a1.z); a1.w = fmaf(v1, m11.w, a1.w);
  }
  if (t < nc) {
    unsigned j0 = si[t]; float v0 = sv[t];
    const float4* r0 = (const float4*)(M + (size_t)j0 * DD);
    float4 m00 = r0[tid], m01 = r0[tid + 256];
    a0.x = fmaf(v0, m00.x, a0.x); a0.y = fmaf(v0, m00.y, a0.y);
    a0.z = fmaf(v0, m00.z, a0.z); a0.w = fmaf(v0, m00.w, a0.w);
    a1.x = fmaf(v0, m01.x, a1.x); a1.y = fmaf(v0, m01.y, a1.y);
    a1.z = fmaf(v0, m01.z, a1.z); a1.w = fmaf(v0, m01.w, a1.w);
  }
  ((float4*)outF)[o4] = a0;
  ((float4*)outF)[o4 + 256] = a1;
}

// ------------------------------------------------------------- attention bits
__global__ __launch_bounds__(256)
void attdot_kernel(const float* __restrict__ prev, const float* __restrict__ U,
                   float* __restrict__ att) {
  const int b = blockIdx.x, p = blockIdx.y, tid = threadIdx.x;
  const float* pr = prev + ((size_t)p*NB + b) * DD;
  const float* u  = U + (size_t)b * DD;
  float s = 0.f;
#pragma unroll
  for (int h = 0; h < 2; ++h) {
    int i = (tid + h*256) * 4;
    float4 a = *(const float4*)&pr[i];
    float4 c = *(const float4*)&u[i];
    s += a.x*c.x + a.y*c.y + a.z*c.z + a.w*c.w;
  }
  for (int off = 32; off; off >>= 1) s += __shfl_down(s, off);
  __shared__ float ps[4];
  if ((tid & 63) == 0) ps[tid >> 6] = s;
  __syncthreads();
  if (tid == 0) att[(size_t)p*NB + b] = ps[0]+ps[1]+ps[2]+ps[3];
}

__global__ __launch_bounds__(256)
void softmax_kernel(const float* __restrict__ att, float* __restrict__ attw) {
  const int p = blockIdx.x, tid = threadIdx.x;
  const float* a = att + (size_t)p*NB;
  float loc[8]; float mx = -3.4e38f;
#pragma unroll
  for (int h = 0; h < 8; ++h) { loc[h] = a[tid + h*256]; mx = fmaxf(mx, loc[h]); }
  for (int off = 32; off; off >>= 1) mx = fmaxf(mx, __shfl_down(mx, off));
  __shared__ float ps[4]; __shared__ float sh_m, sh_s;
  if ((tid & 63) == 0) ps[tid >> 6] = mx;
  __syncthreads();
  if (tid == 0) sh_m = fmaxf(fmaxf(ps[0],ps[1]), fmaxf(ps[2],ps[3]));
  __syncthreads();
  const float m = sh_m;
  float sum = 0.f;
#pragma unroll
  for (int h = 0; h < 8; ++h) sum += expf(loc[h] - m);
  for (int off = 32; off; off >>= 1) sum += __shfl_down(sum, off);
  __syncthreads();
  if ((tid & 63) == 0) ps[tid >> 6] = sum;
  __syncthreads();
  if (tid == 0) sh_s = ps[0]+ps[1]+ps[2]+ps[3];
  __syncthreads();
  const float inv = 1.0f / sh_s;
#pragma unroll
  for (int h = 0; h < 8; ++h) attw[(size_t)p*NB + tid + h*256] = expf(loc[h] - m) * inv;
}

__global__ __launch_bounds__(256)
void zatt_kernel(const float* __restrict__ prev, const float* __restrict__ attw,
                 const float* __restrict__ lam, float* __restrict__ Z) {
  const int b = blockIdx.x, tid = threadIdx.x;
  __shared__ float w[8];
  if (tid < 8) w[tid] = attw[(size_t)tid*NB + b];
  __syncthreads();
  const float l2 = lam[0];
#pragma unroll
  for (int h = 0; h < 2; ++h) {
    int i = (tid + h*256) * 4;
    float4 acc = {0.f,0.f,0.f,0.f};
#pragma unroll
    for (int p = 0; p < 8; ++p) {
      float4 pv = *(const float4*)&prev[((size_t)p*NB + b)*DD + i];
      float wp = w[p];
      acc.x += wp * fminf(fmaxf(pv.x, -150.f), 150.f);
      acc.y += wp * fminf(fmaxf(pv.y, -150.f), 150.f);
      acc.z += wp * fminf(fmaxf(pv.z, -150.f), 150.f);
      acc.w += wp * fminf(fmaxf(pv.w, -150.f), 150.f);
    }
    acc.x *= l2; acc.y *= l2; acc.z *= l2; acc.w *= l2;
    *(float4*)&Z[(size_t)b*DD + i] = acc;
  }
}

__global__ __launch_bounds__(256)
void norm_kernel(float* __restrict__ mD) {
  const int tid = threadIdx.x;
  float v[4]; float mn = 3.4e38f, mx = -3.4e38f;
#pragma unroll
  for (int h = 0; h < 4; ++h) {
    v[h] = mD[tid + h*256];
    mn = fminf(mn, v[h]); mx = fmaxf(mx, v[h]);
  }
  for (int off = 32; off; off >>= 1) {
    mn = fminf(mn, __shfl_down(mn, off));
    mx = fmaxf(mx, __shfl_down(mx, off));
  }
  __shared__ float pmn[4], pmx[4]; __shared__ float smn, smx;
  if ((tid & 63) == 0) { pmn[tid>>6] = mn; pmx[tid>>6] = mx; }
  __syncthreads();
  if (tid == 0) {
    smn = fminf(fminf(pmn[0],pmn[1]), fminf(pmn[2],pmn[3]));
    smx = fmaxf(fmaxf(pmx[0],pmx[1]), fmaxf(pmx[2],pmx[3]));
  }
  __syncthreads();
  const float d = smx - smn + 1e-8f;
#pragma unroll
  for (int h = 0; h < 4; ++h) mD[tid + h*256] = (v[h] - smn) / d;
}

// ----------------------------------------------------------------- launcher
extern "C" void kernel_launch(void* const* d_in, const int* in_sizes, int n_in,
                              void* d_out, int out_size, void* d_ws, size_t ws_size,
                              hipStream_t stream) {
  const float* x    = (const float*)d_in[0];   // (2048, 2048)
  const float* prev = (const float*)d_in[1];   // (8, 2048, 2048)
  const float* Wd   = (const float*)d_in[2];   // (2048, 2048)
  const float* S    = (const float*)d_in[3];   // (2048, 2048) symmetric
  const float* lam  = (const float*)d_in[4];   // scalar

  float* out   = (float*)d_out;
  float* mD    = out;                 // 1024
  float* zlast = out + 1024;          // dense z_last; doubles as U scratch early

  // workspace layout (~49.3 MB)
  float* B  = (float*)d_ws;                       // 16 MB
  float* C  = B  + (1u << 22);                    // 16 MB
  float* X1 = C  + (1u << 22);                    // 16 MB (s_t, then z_att)
  unsigned* sidx = (unsigned*)(X1 + (1u << 22));  // 2048*64 u32
  float*    sval = (float*)(sidx + 2048*64);      // 2048*64 f32
  int*      scnt = (int*)(sval + 2048*64);        // 2048
  float*    att  = (float*)(scnt + 2048);         // 8*2048
  float*    attw = att + 8*2048;                  // 8*2048
  float*    U    = zlast;

  const dim3 gGemm(DD/64, DD/128);    // 32 x 16 = 512 blocks (2/CU)

  // B = x @ Wd^T
  gemm_f32<1,0><<<gGemm, 256, 0, stream>>>(x, Wd, nullptr, B);
  // z1 = hard_thr(B)
  topk_kernel<<<NB, 64, 0, stream>>>(B, sidx, sval, scnt, nullptr, nullptr, 0);
  // C = B + S z1  (sparse, coalesced row gather; S symmetric)
  spapply2<1><<<NB, 256, 0, stream>>>(S, B, C, sidx, sval, scnt);
  // z2 = hard_thr(C)
  topk_kernel<<<NB, 64, 0, stream>>>(C, sidx, sval, scnt, nullptr, nullptr, 0);
  // s_t = Wd^T z2  (sparse rows of Wd)
  spapply2<0><<<NB, 256, 0, stream>>>(Wd, nullptr, X1, sidx, sval, scnt);
  // u = s_t @ Wd
  gemm_f32<0,0><<<gGemm, 256, 0, stream>>>(X1, Wd, nullptr, U);
  // att[p,b] = <prev[p,b,:], u[b,:]>
  attdot_kernel<<<dim3(NB, 8), 256, 0, stream>>>(prev, U, att);
  // softmax over batch axis
  softmax_kernel<<<8, 256, 0, stream>>>(att, attw);
  // z_att = lambda2 * sum_p attw * clip(prev)
  zatt_kernel<<<NB, 256, 0, stream>>>(prev, attw, lam, X1);
  // iter 1 (dense z): C = B + z_att @ S   (S symmetric)
  gemm_f32<0,1><<<gGemm, 256, 0, stream>>>(X1, S, B, C);

  for (int it = 0; it < 10; ++it) {
    if (it > 0)
      spapply2<1><<<NB, 256, 0, stream>>>(S, B, C, sidx, sval, scnt);
    const int fin = (it == 9);
    if (fin) hipMemsetAsync(mD, 0, 1024 * sizeof(float), stream);
    topk_kernel<<<NB, 64, 0, stream>>>(C, sidx, sval, scnt,
                                       fin ? zlast : nullptr,
                                       fin ? mD : nullptr, fin);
  }
  // mD_norm = (mD - min) / (max - min + 1e-8)
  norm_kernel<<<1, 256, 0, stream>>>(mD);
}